// Round 13
// baseline (1543.423 us; speedup 1.0000x reference)
//
#include <hip/hip_runtime.h>

// ---------- types / helpers ----------
typedef __bf16 bf16x8 __attribute__((ext_vector_type(8)));
typedef float  f32x4  __attribute__((ext_vector_type(4)));

// native cast -> compiler emits v_cvt_pk_bf16_f32 (RNE)
__device__ inline unsigned short f2bf(float f){
  __bf16 b = (__bf16)f;
  return __builtin_bit_cast(unsigned short, b);
}
__device__ inline unsigned int pack2bf(float lo, float hi){
  return (unsigned)f2bf(lo) | ((unsigned)f2bf(hi) << 16);
}
__device__ inline float tanh_fast(float x){
  float e = __builtin_amdgcn_exp2f(x * 2.8853900817779268f);
  return 1.0f - 2.0f * __builtin_amdgcn_rcpf(e + 1.0f);
}
__device__ inline float sigmoid_fast(float x){
  float e = __builtin_amdgcn_exp2f(x * -1.4426950408889634f);
  return __builtin_amdgcn_rcpf(1.0f + e);
}
__device__ inline float bflo(unsigned int u){ return __uint_as_float(u << 16); }
__device__ inline float bfhi(unsigned int u){ return __uint_as_float(u & 0xffff0000u); }

// barrier WITHOUT vmem drain (lgkmcnt-only; LDS-safe, proven r7/r8/r12)
__device__ __forceinline__ void bar_nodrain(){
  asm volatile("s_waitcnt lgkmcnt(0)" ::: "memory");
  __builtin_amdgcn_s_barrier();
}

// position of the n-th set bit; returns 0 if n >= popcount(m) (caller predicates)
__device__ inline int nthbit(unsigned long long m, int n){
  for (int k = 0; k < n; k++) m &= m - 1;
  return m ? (int)__builtin_ctzll(m) : 0;
}

// ---------- counts ----------
__global__ void k_count(const int* __restrict__ ei, int* __restrict__ cnt, int E){
  int e = blockIdx.x * 256 + threadIdx.x;
  if (e < E) atomicAdd(&cnt[ei[E + e]], 1);
}

// ---------- exclusive scan of (cnt[v]+1) ----------
__global__ __launch_bounds__(1024) void k_scan(const int* __restrict__ cnt, int* __restrict__ cursor, int N){
  __shared__ int partial[1024];
  int t = threadIdx.x;
  int chunk = (N + 1023) / 1024;
  int lo = t * chunk, hi = min(lo + chunk, N);
  int s = 0;
  for (int v = lo; v < hi; v++) s += cnt[v] + 1;
  partial[t] = s;
  __syncthreads();
  for (int off = 1; off < 1024; off <<= 1){
    int val = (t >= off) ? partial[t - off] : 0;
    __syncthreads();
    partial[t] += val;
    __syncthreads();
  }
  int base = (t == 0) ? 0 : partial[t - 1];
  for (int v = lo; v < hi; v++){ cursor[v] = base; base += cnt[v] + 1; }
}

// ---------- counting-sort scatter by dst ----------
__global__ void k_scatter(const int* __restrict__ ei, int* __restrict__ cursor,
                          int* __restrict__ srcS, int* __restrict__ dstS, int E, int N){
  int i = blockIdx.x * 256 + threadIdx.x;
  int Et = E + N;
  if (i >= Et) return;
  int s, d;
  if (i < E){ s = ei[i]; d = ei[E + i]; } else { s = d = i - E; }
  int pos = atomicAdd(&cursor[d], 1);
  srcS[pos] = s; dstS[pos] = d;
}

// ---------- weight prep: W1T, W2T ----------
__global__ void k_wprep(const float* __restrict__ msgW1, const float* __restrict__ msgW2,
                        unsigned short* __restrict__ W1T, unsigned short* __restrict__ W2T){
  int idx = blockIdx.x * 256 + threadIdx.x;
  if (idx < 3 * 256 * 256){
    int l = idx >> 16, r = idx & 65535; int n = r >> 8, k = r & 255;
    W1T[idx] = f2bf(msgW1[(size_t)l * 65536 + k * 256 + n]);
  }
  int i2 = idx - 3 * 65536;
  if (i2 >= 0 && i2 < 3 * 128 * 256){
    int l = i2 >> 15, r = i2 & 32767; int hh = r >> 8, k = r & 255;
    W2T[i2] = f2bf(msgW2[(size_t)l * 32768 + k * 128 + hh]);
  }
}

// ---------- weight prep: W0T[l][half][c][k] ----------
__global__ void k_wprep2(const float* __restrict__ msgW0, unsigned short* __restrict__ W0T){
  int idx = blockIdx.x * 256 + threadIdx.x;
  if (idx >= 3 * 2 * 256 * 128) return;
  int l = idx / 65536, r = idx % 65536;
  int half = r >> 15, r2 = r & 32767, c = r2 >> 7, k = r2 & 127;
  W0T[idx] = f2bf(msgW0[(size_t)l * 65536 + (half * 128 + k) * 256 + c]);
}

// ---------- weight prep: Wcat[l][j][k] = [Wih[j] || Whh[j]] ----------
__global__ void k_wprep3(const float* __restrict__ gWih, const float* __restrict__ gWhh,
                         unsigned short* __restrict__ Wcat){
  int idx = blockIdx.x * 256 + threadIdx.x;
  if (idx >= 3 * 384 * 256) return;
  int l = idx / 98304, r = idx % 98304, j = r >> 8, k = r & 255;
  float v = (k < 128) ? gWih[((size_t)l * 384 + j) * 128 + k]
                      : gWhh[((size_t)l * 384 + j) * 128 + (k - 128)];
  Wcat[idx] = f2bf(v);
}

// ---------- weight prep: encWT, dW0T, dW1T, GRU biases ----------
__global__ void k_wprep4(const float* __restrict__ encW, const float* __restrict__ dW0,
                         const float* __restrict__ dW1,
                         const float* __restrict__ gbih, const float* __restrict__ gbhh,
                         unsigned short* __restrict__ encWT, unsigned short* __restrict__ dW0T,
                         unsigned short* __restrict__ dW1T,
                         float* __restrict__ brz, float* __restrict__ bin, float* __restrict__ bhn){
  int idx = blockIdx.x * 256 + threadIdx.x;
  if (idx < 8192){ int c = idx >> 6, k = idx & 63; encWT[idx] = f2bf(encW[k * 128 + c]); return; }
  idx -= 8192;
  if (idx < 32768){ int c = idx >> 7, k = idx & 127; dW0T[idx] = f2bf(dW0[k * 256 + c]); return; }
  idx -= 32768;
  if (idx < 65536){ int c = idx >> 8, k = idx & 255; dW1T[idx] = f2bf(dW1[k * 256 + c]); return; }
  idx -= 65536;
  if (idx < 768){ int l = idx >> 8, j = idx & 255; brz[idx] = gbih[l * 384 + j] + gbhh[l * 384 + j]; return; }
  idx -= 768;
  if (idx < 384){ int l = idx >> 7, j = idx & 127; bin[idx] = gbih[l * 384 + 256 + j]; return; }
  idx -= 384;
  if (idx < 384){ int l = idx >> 7, j = idx & 127; bhn[idx] = gbhh[l * 384 + 256 + j]; return; }
}

// ---------- shared A/B-projection body: reads hn (bf16 LDS, [64][256B] swizzled)
// A = h@W0a + b0 (bias in C-in), B = h@W0b; writes bf16 to global A/B.
__device__ __forceinline__ void ab_body(const unsigned char* hn,
        const unsigned short* __restrict__ W0T, const float* __restrict__ b0,
        unsigned short* __restrict__ A, unsigned short* __restrict__ B,
        int n0, int N, int wv, int l15, int kg){
  f32x4 zero = {0.f, 0.f, 0.f, 0.f};
  int c64 = wv * 64;
  f32x4 accA[4][4], accB[4][4];
  #pragma unroll
  for (int ct = 0; ct < 4; ct++){
    int c = c64 + ct * 16 + kg * 4;
    float4 b4 = *(const float4*)(b0 + c);
    f32x4 binit = {b4.x, b4.y, b4.z, b4.w};
    #pragma unroll
    for (int b_ = 0; b_ < 4; b_++){ accA[ct][b_] = binit; accB[ct][b_] = zero; }
  }
  const unsigned char* wa = (const unsigned char*)W0T;       // [256][256B]
  const unsigned char* wb = wa + 65536;
  #pragma unroll
  for (int ks = 0; ks < 4; ks++){
    int koff = ks * 64 + kg * 16;
    bf16x8 bfr[4];
    #pragma unroll
    for (int nt = 0; nt < 4; nt++){
      int row = nt * 16 + l15;
      bfr[nt] = *(const bf16x8*)(hn + row * 256 + (koff ^ ((row & 7) << 4)));
    }
    bf16x8 afA[4], afB[4];
    #pragma unroll
    for (int ct = 0; ct < 4; ct++){
      int r = c64 + ct * 16 + l15;
      afA[ct] = *(const bf16x8*)(wa + (size_t)r * 256 + koff);
      afB[ct] = *(const bf16x8*)(wb + (size_t)r * 256 + koff);
    }
    #pragma unroll
    for (int ct = 0; ct < 4; ct++)
      #pragma unroll
      for (int nt = 0; nt < 4; nt++){
        accA[ct][nt] = __builtin_amdgcn_mfma_f32_16x16x32_bf16(afA[ct], bfr[nt], accA[ct][nt], 0, 0, 0);
        accB[ct][nt] = __builtin_amdgcn_mfma_f32_16x16x32_bf16(afB[ct], bfr[nt], accB[ct][nt], 0, 0, 0);
      }
  }
  #pragma unroll
  for (int ct = 0; ct < 4; ct++){
    int c = c64 + ct * 16 + kg * 4;
    #pragma unroll
    for (int nt = 0; nt < 4; nt++){
      int node = n0 + nt * 16 + l15;
      if (node >= N) continue;
      f32x4 va = accA[ct][nt], vb = accB[ct][nt];
      uint2 oa, ob;
      oa.x = pack2bf(va[0], va[1]); oa.y = pack2bf(va[2], va[3]);
      ob.x = pack2bf(vb[0], vb[1]); ob.y = pack2bf(vb[2], vb[3]);
      *(uint2*)(A + (size_t)node * 256 + c) = oa;
      *(uint2*)(B + (size_t)node * 256 + c) = ob;
    }
  }
}

// ---------- encoder + fused A/B projection (layer 0), 64 nodes/block ----------
__global__ __launch_bounds__(256) void k_enc(const float* __restrict__ x,
        const unsigned short* __restrict__ encWT, const float* __restrict__ encb,
        const unsigned short* __restrict__ W0T0, const float* __restrict__ b00,
        float* __restrict__ h, unsigned short* __restrict__ hb,
        unsigned short* __restrict__ A, unsigned short* __restrict__ B, int N){
  __shared__ __align__(16) unsigned char xb[64 * 128];
  __shared__ __align__(16) unsigned char hn[64 * 256];   // hnew bf16, ab_body layout
  int n0 = blockIdx.x * 64, t = threadIdx.x;
  // zero hn (node>=N rows must not be NaN garbage)
  #pragma unroll
  for (int i = 0; i < 4; i++)
    *(uint4*)(hn + (t + i * 256) * 16) = make_uint4(0, 0, 0, 0);
  #pragma unroll
  for (int p = 0; p < 2; p++){
    int i = t + p * 256;
    int row = i >> 3, ch = i & 7;
    int node = n0 + row;
    unsigned int o[4] = {0,0,0,0};
    if (node < N){
      const float* s = x + (size_t)node * 64 + ch * 8;
      float4 a = *(const float4*)s, b = *(const float4*)(s + 4);
      o[0] = pack2bf(a.x, a.y);
      o[1] = pack2bf(a.z, a.w);
      o[2] = pack2bf(b.x, b.y);
      o[3] = pack2bf(b.z, b.w);
    }
    *(uint4*)(xb + row * 128 + ((ch * 16) ^ ((row & 7) << 4))) = make_uint4(o[0], o[1], o[2], o[3]);
  }
  __syncthreads();
  int wv = t >> 6, lane = t & 63, l15 = lane & 15, kg = lane >> 4;
  int c32 = wv * 32;
  f32x4 acc[2][4];
  #pragma unroll
  for (int ct = 0; ct < 2; ct++){
    int c = c32 + ct * 16 + kg * 4;
    float4 be = *(const float4*)(encb + c);
    f32x4 binit = {be.x, be.y, be.z, be.w};
    #pragma unroll
    for (int b_ = 0; b_ < 4; b_++) acc[ct][b_] = binit;
  }
  const unsigned char* wp = (const unsigned char*)encWT;   // [128][128B]
  #pragma unroll
  for (int ks = 0; ks < 2; ks++){
    int koff = ks * 64 + kg * 16;
    bf16x8 bfr[4], afr[2];
    #pragma unroll
    for (int nt = 0; nt < 4; nt++){
      int row = nt * 16 + l15;
      bfr[nt] = *(const bf16x8*)(xb + row * 128 + (koff ^ ((row & 7) << 4)));
    }
    #pragma unroll
    for (int ct = 0; ct < 2; ct++)
      afr[ct] = *(const bf16x8*)(wp + (size_t)(c32 + ct * 16 + l15) * 128 + koff);
    #pragma unroll
    for (int ct = 0; ct < 2; ct++)
      #pragma unroll
      for (int nt = 0; nt < 4; nt++)
        acc[ct][nt] = __builtin_amdgcn_mfma_f32_16x16x32_bf16(afr[ct], bfr[nt], acc[ct][nt], 0, 0, 0);
  }
  #pragma unroll
  for (int ct = 0; ct < 2; ct++){
    int c = c32 + ct * 16 + kg * 4;
    #pragma unroll
    for (int nt = 0; nt < 4; nt++){
      int row = nt * 16 + l15;
      int node = n0 + row;
      if (node >= N) continue;
      f32x4 v = acc[ct][nt];
      float o0 = tanh_fast(v[0]), o1 = tanh_fast(v[1]);
      float o2 = tanh_fast(v[2]), o3 = tanh_fast(v[3]);
      float4 fo; fo.x = o0; fo.y = o1; fo.z = o2; fo.w = o3;
      *(float4*)(h + (size_t)node * 128 + c) = fo;
      uint2 bo; bo.x = pack2bf(o0, o1); bo.y = pack2bf(o2, o3);
      *(uint2*)(hb + (size_t)node * 128 + c) = bo;
      *(uint2*)(hn + row * 256 + ((((c >> 3) << 4) ^ ((row & 7) << 4)) + ((c & 7) << 1))) = bo;
    }
  }
  __syncthreads();
  ab_body(hn, W0T0, b00, A, B, n0, N, wv, l15, kg);
}

// ---------- fused edge MLP + segmented aggregation (r12, verified) ----------
__global__ __launch_bounds__(256, 4) void k_edge(
        const int* __restrict__ srcS, const int* __restrict__ dstS,
        const unsigned short* __restrict__ Abuf, const unsigned short* __restrict__ Bbuf,
        const unsigned short* __restrict__ W1T, const unsigned short* __restrict__ W2T,
        const float* __restrict__ b1, const float* __restrict__ b2,
        float* __restrict__ aggr){
  __shared__ __align__(16) unsigned char lds[40960];  // [0,32768): t0 (bf16) -> m (f32); [32768,40960): t1q
  unsigned char* t0  = lds;
  unsigned char* t1q = lds + 32768;
  int t = threadIdx.x;
  int wv = t >> 6, lane = t & 63, l15 = lane & 15, kg = lane >> 4;
  int e0 = blockIdx.x * 64;

  int sv = srcS[e0 + lane];
  int dv = dstS[e0 + lane];

  int chunk = lane & 31;
  int rbase = wv * 2 + (lane >> 5);
  uint4 av[8], bv[8];
  #pragma unroll
  for (int p = 0; p < 8; p++){
    int row = p * 8 + rbase;
    int d = __shfl(dv, row), s = __shfl(sv, row);
    if (d >= 0){
      av[p] = *(const uint4*)(Abuf + (size_t)d * 256 + chunk * 8);
      bv[p] = *(const uint4*)(Bbuf + (size_t)s * 256 + chunk * 8);
    } else { av[p] = make_uint4(0,0,0,0); bv[p] = make_uint4(0,0,0,0); }
  }

  int prevd = __shfl(dv, (lane == 0) ? 0 : (lane - 1));
  bool valid = (dv >= 0);
  bool flag  = valid && (lane == 0 || prevd != dv);
  unsigned long long sm  = __ballot(flag);
  unsigned long long ivm = __ballot(!valid);
  int nseg   = (int)__popcll(sm);
  int endAll = 64 - (int)__popcll(ivm);

  int segSt, segEn, segD;
  {
    int st_ = nthbit(sm, lane);
    int en_ = (lane + 1 < nseg) ? nthbit(sm, lane + 1) : endAll;
    segSt = st_; segEn = en_;
    segD  = __shfl(dv, st_);
  }

  #pragma unroll
  for (int p = 0; p < 8; p++){
    int r = p * 8 + rbase;
    unsigned int o[4]; unsigned int ua, ub;
    ua = av[p].x; ub = bv[p].x;
    o[0] = pack2bf(tanh_fast(bflo(ua)+bflo(ub)), tanh_fast(bfhi(ua)+bfhi(ub)));
    ua = av[p].y; ub = bv[p].y;
    o[1] = pack2bf(tanh_fast(bflo(ua)+bflo(ub)), tanh_fast(bfhi(ua)+bfhi(ub)));
    ua = av[p].z; ub = bv[p].z;
    o[2] = pack2bf(tanh_fast(bflo(ua)+bflo(ub)), tanh_fast(bfhi(ua)+bfhi(ub)));
    ua = av[p].w; ub = bv[p].w;
    o[3] = pack2bf(tanh_fast(bflo(ua)+bflo(ub)), tanh_fast(bfhi(ua)+bfhi(ub)));
    *(uint4*)(t0 + r * 512 + ((chunk * 16) ^ ((r & 7) << 4))) = make_uint4(o[0],o[1],o[2],o[3]);
  }
  bar_nodrain();

  const unsigned char* w1b = (const unsigned char*)W1T;
  const unsigned char* w2b = (const unsigned char*)W2T;
  int hbase = wv * 32;

  f32x4 acc2[2][4];
  #pragma unroll
  for (int ht = 0; ht < 2; ht++){
    int hb_ = hbase + ht * 16 + kg * 4;
    float4 c4 = *(const float4*)(b2 + hb_);
    f32x4 binit = {c4.x, c4.y, c4.z, c4.w};
    #pragma unroll
    for (int b_ = 0; b_ < 4; b_++) acc2[ht][b_] = binit;
  }

  #pragma unroll
  for (int pass = 0; pass < 4; pass++){
    {
      int nbase = pass * 64 + wv * 16;
      f32x4 acc[4];
      {
        int ng = nbase + kg * 4;
        float4 c4 = *(const float4*)(b1 + ng);
        f32x4 binit = {c4.x, c4.y, c4.z, c4.w};
        #pragma unroll
        for (int b_ = 0; b_ < 4; b_++) acc[b_] = binit;
      }
      #pragma unroll
      for (int ks = 0; ks < 8; ks++){
        int koff = ks * 64 + kg * 16;
        bf16x8 afr = *(const bf16x8*)(w1b + (size_t)(nbase + l15) * 512 + koff);
        bf16x8 bfr[4];
        #pragma unroll
        for (int et = 0; et < 4; et++){
          int row = et * 16 + l15;
          bfr[et] = *(const bf16x8*)(t0 + row * 512 + (koff ^ ((row & 7) << 4)));
        }
        #pragma unroll
        for (int et = 0; et < 4; et++)
          acc[et] = __builtin_amdgcn_mfma_f32_16x16x32_bf16(afr, bfr[et], acc[et], 0, 0, 0);
      }
      int nl2 = (wv * 16 + kg * 4) * 2;
      #pragma unroll
      for (int et = 0; et < 4; et++){
        int edge = et * 16 + l15;
        f32x4 v = acc[et];
        unsigned int p0 = pack2bf(tanh_fast(v[0]), tanh_fast(v[1]));
        unsigned int p1 = pack2bf(tanh_fast(v[2]), tanh_fast(v[3]));
        *(uint2*)(t1q + edge * 128 + (nl2 ^ ((edge & 7) << 4))) = make_uint2(p0, p1);
      }
    }
    bar_nodrain();

    #pragma unroll
    for (int ks = 0; ks < 2; ks++){
      int koff  = ks * 64 + kg * 16;
      int wkoff = pass * 128 + koff;
      bf16x8 afr[2], bfr[4];
      #pragma unroll
      for (int ht = 0; ht < 2; ht++)
        afr[ht] = *(const bf16x8*)(w2b + (size_t)(hbase + ht * 16 + l15) * 512 + wkoff);
      #pragma unroll
      for (int et = 0; et < 4; et++){
        int row = et * 16 + l15;
        bfr[et] = *(const bf16x8*)(t1q + row * 128 + (koff ^ ((row & 7) << 4)));
      }
      #pragma unroll
      for (int ht = 0; ht < 2; ht++)
        #pragma unroll
        for (int et = 0; et < 4; et++)
          acc2[ht][et] = __builtin_amdgcn_mfma_f32_16x16x32_bf16(afr[ht], bfr[et], acc2[ht][et], 0, 0, 0);
    }
    bar_nodrain();
  }

  #pragma unroll
  for (int ht = 0; ht < 2; ht++){
    int hb_ = hbase + ht * 16 + kg * 4;
    int cch = hb_ >> 2;
    #pragma unroll
    for (int et = 0; et < 4; et++){
      int edge = et * 16 + l15;
      f32x4 v = acc2[ht][et];
      float4 o; o.x = v[0]; o.y = v[1]; o.z = v[2]; o.w = v[3];
      *(float4*)(t0 + edge * 512 + ((cch ^ (edge & 7)) << 4)) = o;
    }
  }
  bar_nodrain();

  {
    int c = lane & 31;
    int sstr = wv * 2 + (lane >> 5);
    #pragma unroll
    for (int s0 = 0; s0 < 8; s0++){
      int s = sstr + s0 * 8;
      int st = __shfl(segSt, s);
      int en = __shfl(segEn, s);
      int d  = __shfl(segD,  s);
      if (s < nseg){
        float4 sum; sum.x = sum.y = sum.z = sum.w = 0.f;
        for (int e = st; e < en; e++){
          float4 v = *(const float4*)(t0 + e * 512 + ((c ^ (e & 7)) << 4));
          sum.x += v.x; sum.y += v.y; sum.z += v.z; sum.w += v.w;
        }
        float* base = aggr + (size_t)d * 128 + c * 4;
        atomicAdd(base + 0, sum.x);
        atomicAdd(base + 1, sum.y);
        atomicAdd(base + 2, sum.z);
        atomicAdd(base + 3, sum.w);
      }
    }
  }
}

// ---------- GRU cell update + fused next-layer A/B, 64 nodes/block ----------
__global__ __launch_bounds__(256) void k_gru(const float* __restrict__ aggr, const int* __restrict__ cnt,
    float* __restrict__ h, unsigned short* __restrict__ hb,
    const unsigned short* __restrict__ Wcat, const float* __restrict__ brz,
    const float* __restrict__ bin, const float* __restrict__ bhn,
    int doAB, const unsigned short* __restrict__ W0Tn, const float* __restrict__ b0n,
    unsigned short* __restrict__ A, unsigned short* __restrict__ B, int N){
  __shared__ __align__(16) unsigned char u[64 * 512];   // [aggr*inv || h] bf16; later hnew (first 16KB)
  __shared__ __align__(16) unsigned char hf[64 * 512];  // h f32 swizzled
  int n0 = blockIdx.x * 64, t = threadIdx.x;
  {
    int row = t >> 2, node = n0 + row;
    int q4 = t & 3;
    bool isA = q4 < 2;
    float inv = 0.f;
    if (isA && node < N) inv = __builtin_amdgcn_rcpf((float)(cnt[node] + 1));
    #pragma unroll
    for (int p = 0; p < 8; p++){
      int ch = q4 * 8 + p;
      unsigned int o[4] = {0,0,0,0};
      if (node < N){
        if (isA){
          const float* s = aggr + (size_t)node * 128 + ch * 8;
          float4 a = *(const float4*)s, b = *(const float4*)(s + 4);
          a.x *= inv; a.y *= inv; a.z *= inv; a.w *= inv;
          b.x *= inv; b.y *= inv; b.z *= inv; b.w *= inv;
          o[0] = pack2bf(a.x, a.y); o[1] = pack2bf(a.z, a.w);
          o[2] = pack2bf(b.x, b.y); o[3] = pack2bf(b.z, b.w);
        } else {
          const float* s = h + (size_t)node * 128 + (ch - 16) * 8;
          float4 a = *(const float4*)s, b = *(const float4*)(s + 4);
          o[0] = pack2bf(a.x, a.y); o[1] = pack2bf(a.z, a.w);
          o[2] = pack2bf(b.x, b.y); o[3] = pack2bf(b.z, b.w);
          int c2 = (ch - 16) * 2;
          *(float4*)(hf + row * 512 + ((c2 * 16) ^ ((row & 7) << 4))) = a;
          *(float4*)(hf + row * 512 + (((c2 + 1) * 16) ^ ((row & 7) << 4))) = b;
        }
      }
      *(uint4*)(u + row * 512 + ((ch * 16) ^ ((row & 7) << 4))) = make_uint4(o[0], o[1], o[2], o[3]);
    }
  }
  __syncthreads();
  int wv = t >> 6, lane = t & 63, l15 = lane & 15, kg = lane >> 4;
  int j32 = wv * 32;
  f32x4 accR[2][4], accZ[2][4], accI[2][4], accH[2][4];
  #pragma unroll
  for (int jt = 0; jt < 2; jt++){
    int j = j32 + jt * 16 + kg * 4;
    float4 br = *(const float4*)(brz + j);
    float4 bz = *(const float4*)(brz + 128 + j);
    float4 bi = *(const float4*)(bin + j);
    float4 bh = *(const float4*)(bhn + j);
    f32x4 vr = {br.x, br.y, br.z, br.w};
    f32x4 vz = {bz.x, bz.y, bz.z, bz.w};
    f32x4 vi = {bi.x, bi.y, bi.z, bi.w};
    f32x4 vh = {bh.x, bh.y, bh.z, bh.w};
    #pragma unroll
    for (int b_ = 0; b_ < 4; b_++){ accR[jt][b_] = vr; accZ[jt][b_] = vz; accI[jt][b_] = vi; accH[jt][b_] = vh; }
  }
  const unsigned char* wc = (const unsigned char*)Wcat;     // [384][512B]
  #pragma unroll
  for (int ks = 0; ks < 8; ks++){
    int koff = ks * 64 + kg * 16;
    bf16x8 bfr[4];
    #pragma unroll
    for (int nt = 0; nt < 4; nt++){
      int row = nt * 16 + l15;
      bfr[nt] = *(const bf16x8*)(u + row * 512 + (koff ^ ((row & 7) << 4)));
    }
    bf16x8 aR[2], aZ[2], aN[2];
    #pragma unroll
    for (int jt = 0; jt < 2; jt++){
      int jr = j32 + jt * 16 + l15;
      aR[jt] = *(const bf16x8*)(wc + (size_t)jr * 512 + koff);
      aZ[jt] = *(const bf16x8*)(wc + (size_t)(128 + jr) * 512 + koff);
      aN[jt] = *(const bf16x8*)(wc + (size_t)(256 + jr) * 512 + koff);
    }
    #pragma unroll
    for (int jt = 0; jt < 2; jt++)
      #pragma unroll
      for (int nt = 0; nt < 4; nt++){
        accR[jt][nt] = __builtin_amdgcn_mfma_f32_16x16x32_bf16(aR[jt], bfr[nt], accR[jt][nt], 0, 0, 0);
        accZ[jt][nt] = __builtin_amdgcn_mfma_f32_16x16x32_bf16(aZ[jt], bfr[nt], accZ[jt][nt], 0, 0, 0);
      }
    if (ks < 4){
      #pragma unroll
      for (int jt = 0; jt < 2; jt++)
        #pragma unroll
        for (int nt = 0; nt < 4; nt++)
          accI[jt][nt] = __builtin_amdgcn_mfma_f32_16x16x32_bf16(aN[jt], bfr[nt], accI[jt][nt], 0, 0, 0);
    } else {
      #pragma unroll
      for (int jt = 0; jt < 2; jt++)
        #pragma unroll
        for (int nt = 0; nt < 4; nt++)
          accH[jt][nt] = __builtin_amdgcn_mfma_f32_16x16x32_bf16(aN[jt], bfr[nt], accH[jt][nt], 0, 0, 0);
    }
  }
  // all u reads done before hnew overwrites it
  __syncthreads();
  #pragma unroll
  for (int jt = 0; jt < 2; jt++){
    int j = j32 + jt * 16 + kg * 4;
    #pragma unroll
    for (int nt = 0; nt < 4; nt++){
      int rloc = nt * 16 + l15;
      int node = n0 + rloc;
      if (node >= N) continue;
      float4 hold = *(const float4*)(hf + rloc * 512 + ((j * 4) ^ ((rloc & 7) << 4)));
      f32x4 vr = accR[jt][nt], vz = accZ[jt][nt], vi = accI[jt][nt], vh = accH[jt][nt];
      float o[4];
      {
        float r0 = sigmoid_fast(vr[0]), z0 = sigmoid_fast(vz[0]);
        o[0] = (1.f - z0) * tanh_fast(vi[0] + r0 * vh[0]) + z0 * hold.x;
        float r1 = sigmoid_fast(vr[1]), z1 = sigmoid_fast(vz[1]);
        o[1] = (1.f - z1) * tanh_fast(vi[1] + r1 * vh[1]) + z1 * hold.y;
        float r2 = sigmoid_fast(vr[2]), z2 = sigmoid_fast(vz[2]);
        o[2] = (1.f - z2) * tanh_fast(vi[2] + r2 * vh[2]) + z2 * hold.z;
        float r3 = sigmoid_fast(vr[3]), z3 = sigmoid_fast(vz[3]);
        o[3] = (1.f - z3) * tanh_fast(vi[3] + r3 * vh[3]) + z3 * hold.w;
      }
      float4 fo; fo.x = o[0]; fo.y = o[1]; fo.z = o[2]; fo.w = o[3];
      *(float4*)(h + (size_t)node * 128 + j) = fo;
      uint2 bo; bo.x = pack2bf(o[0], o[1]); bo.y = pack2bf(o[2], o[3]);
      *(uint2*)(hb + (size_t)node * 128 + j) = bo;
      // hnew into u (first 16KB, 256B rows, ab_body layout). Invalid rows keep
      // staged finite values; their A/B columns are discarded at the guard.
      *(uint2*)(u + rloc * 256 + ((((j >> 3) << 4) ^ ((rloc & 7) << 4)) + ((j & 7) << 1))) = bo;
    }
  }
  if (doAB){
    __syncthreads();
    ab_body(u, W0Tn, b0n, A, B, n0, N, wv, l15, kg);
  }
}

// ---------- decoder: MFMA, 64 nodes/block ----------
__global__ __launch_bounds__(256) void k_dec(const unsigned short* __restrict__ hb,
    const unsigned short* __restrict__ dW0T, const float* __restrict__ db0,
    const unsigned short* __restrict__ dW1T, const float* __restrict__ db1,
    const float* __restrict__ dW2, const float* __restrict__ db2,
    float* __restrict__ out, int N){
  __shared__ __align__(16) unsigned char ub[64 * 256];
  __shared__ __align__(16) unsigned char y1[64 * 512];
  __shared__ __align__(16) unsigned char y2[64 * 1024];
  int n0 = blockIdx.x * 64, t = threadIdx.x;
  #pragma unroll
  for (int p = 0; p < 4; p++){
    int i = t + p * 256;
    int row = i >> 4, ch = i & 15;
    int node = n0 + row;
    uint4 v = (node < N) ? *(const uint4*)(hb + (size_t)node * 128 + ch * 8) : make_uint4(0,0,0,0);
    *(uint4*)(ub + row * 256 + ((ch * 16) ^ ((row & 7) << 4))) = v;
  }
  __syncthreads();
  int wv = t >> 6, lane = t & 63, l15 = lane & 15, kg = lane >> 4;
  int c64 = wv * 64;
  {
    f32x4 acc[4][4];
    #pragma unroll
    for (int ct = 0; ct < 4; ct++){
      int c = c64 + ct * 16 + kg * 4;
      float4 b4 = *(const float4*)(db0 + c);
      f32x4 binit = {b4.x, b4.y, b4.z, b4.w};
      #pragma unroll
      for (int b_ = 0; b_ < 4; b_++) acc[ct][b_] = binit;
    }
    const unsigned char* wp = (const unsigned char*)dW0T;   // [256][256B]
    #pragma unroll
    for (int ks = 0; ks < 4; ks++){
      int koff = ks * 64 + kg * 16;
      bf16x8 bfr[4], afr[4];
      #pragma unroll
      for (int nt = 0; nt < 4; nt++){
        int row = nt * 16 + l15;
        bfr[nt] = *(const bf16x8*)(ub + row * 256 + (koff ^ ((row & 7) << 4)));
      }
      #pragma unroll
      for (int ct = 0; ct < 4; ct++)
        afr[ct] = *(const bf16x8*)(wp + (size_t)(c64 + ct * 16 + l15) * 256 + koff);
      #pragma unroll
      for (int ct = 0; ct < 4; ct++)
        #pragma unroll
        for (int nt = 0; nt < 4; nt++)
          acc[ct][nt] = __builtin_amdgcn_mfma_f32_16x16x32_bf16(afr[ct], bfr[nt], acc[ct][nt], 0, 0, 0);
    }
    #pragma unroll
    for (int ct = 0; ct < 4; ct++){
      int c = c64 + ct * 16 + kg * 4;
      #pragma unroll
      for (int nt = 0; nt < 4; nt++){
        int row = nt * 16 + l15;
        f32x4 v = acc[ct][nt];
        unsigned int p0 = pack2bf(tanh_fast(v[0]), tanh_fast(v[1]));
        unsigned int p1 = pack2bf(tanh_fast(v[2]), tanh_fast(v[3]));
        *(uint2*)(y1 + row * 512 + ((c * 2) ^ ((row & 7) << 4))) = make_uint2(p0, p1);
      }
    }
  }
  __syncthreads();
  {
    f32x4 acc[4][4];
    #pragma unroll
    for (int ct = 0; ct < 4; ct++){
      int c = c64 + ct * 16 + kg * 4;
      float4 b4 = *(const float4*)(db1 + c);
      f32x4 binit = {b4.x, b4.y, b4.z, b4.w};
      #pragma unroll
      for (int b_ = 0; b_ < 4; b_++) acc[ct][b_] = binit;
    }
    const unsigned char* wp = (const unsigned char*)dW1T;   // [256][512B]
    #pragma unroll
    for (int ks = 0; ks < 8; ks++){
      int koff = ks * 64 + kg * 16;
      bf16x8 bfr[4], afr[4];
      #pragma unroll
      for (int nt = 0; nt < 4; nt++){
        int row = nt * 16 + l15;
        bfr[nt] = *(const bf16x8*)(y1 + row * 512 + (koff ^ ((row & 7) << 4)));
      }
      #pragma unroll
      for (int ct = 0; ct < 4; ct++)
        afr[ct] = *(const bf16x8*)(wp + (size_t)(c64 + ct * 16 + l15) * 512 + koff);
      #pragma unroll
      for (int ct = 0; ct < 4; ct++)
        #pragma unroll
        for (int nt = 0; nt < 4; nt++)
          acc[ct][nt] = __builtin_amdgcn_mfma_f32_16x16x32_bf16(afr[ct], bfr[nt], acc[ct][nt], 0, 0, 0);
    }
    #pragma unroll
    for (int ct = 0; ct < 4; ct++){
      int c = c64 + ct * 16 + kg * 4;
      #pragma unroll
      for (int nt = 0; nt < 4; nt++){
        int row = nt * 16 + l15;
        f32x4 v = acc[ct][nt];
        float4 o;
        o.x = tanh_fast(v[0]); o.y = tanh_fast(v[1]);
        o.z = tanh_fast(v[2]); o.w = tanh_fast(v[3]);
        *(float4*)(y2 + row * 1024 + ((c * 4) ^ ((row & 7) << 4))) = o;
      }
    }
  }
  __syncthreads();
  {
    int node = t >> 2, part = t & 3;
    float p = 0.f;
    #pragma unroll
    for (int q = 0; q < 16; q++){
      int c = part * 64 + q * 4;
      float4 v = *(const float4*)(y2 + node * 1024 + ((c * 4) ^ ((node & 7) << 4)));
      float4 w = *(const float4*)(dW2 + c);
      p += v.x * w.x + v.y * w.y + v.z * w.z + v.w * w.w;
    }
    p += __shfl_down(p, 2, 4);
    p += __shfl_down(p, 1, 4);
    if (part == 0 && (n0 + node) < N) out[n0 + node] = p + db2[0];
  }
}

// ---------- launcher ----------
extern "C" void kernel_launch(void* const* d_in, const int* in_sizes, int n_in,
                              void* d_out, int out_size, void* d_ws, size_t ws_size,
                              hipStream_t stream){
  const float* x     = (const float*)d_in[0];
  const int*   ei    = (const int*)  d_in[1];
  const float* encW  = (const float*)d_in[2];
  const float* encb  = (const float*)d_in[3];
  const float* msgW0 = (const float*)d_in[4];
  const float* msgb0 = (const float*)d_in[5];
  const float* msgW1 = (const float*)d_in[6];
  const float* msgb1 = (const float*)d_in[7];
  const float* msgW2 = (const float*)d_in[8];
  const float* msgb2 = (const float*)d_in[9];
  const float* gWih  = (const float*)d_in[10];
  const float* gWhh  = (const float*)d_in[11];
  const float* gbih  = (const float*)d_in[12];
  const float* gbhh  = (const float*)d_in[13];
  const float* dW0   = (const float*)d_in[14];
  const float* db0   = (const float*)d_in[15];
  const float* dW1   = (const float*)d_in[16];
  const float* db1   = (const float*)d_in[17];
  const float* dW2   = (const float*)d_in[18];
  const float* db2   = (const float*)d_in[19];
  int N = in_sizes[0] / 64;
  int E = in_sizes[1] / 2;
  float* out = (float*)d_out;

  int Et = E + N;
  int EtPad = (Et + 63) & ~63;

  char* ws = (char*)d_ws;
  size_t off = 0;
  auto alloc = [&](size_t bytes)->void*{
    void* p = ws + off; off += (bytes + 255) & ~(size_t)255; return p;
  };
  float*          h      = (float*)         alloc((size_t)N * 128 * 4);
  unsigned short* hbuf   = (unsigned short*)alloc((size_t)N * 128 * 2);
  unsigned short* Abuf   = (unsigned short*)alloc((size_t)N * 256 * 2);
  unsigned short* Bbuf   = (unsigned short*)alloc((size_t)N * 256 * 2);
  float*          aggr   = (float*)         alloc((size_t)N * 128 * 4);
  int*            cnt    = (int*)           alloc((size_t)N * 4);
  int*            cursor = (int*)           alloc((size_t)N * 4);
  int*            srcS   = (int*)           alloc((size_t)EtPad * 4);
  int*            dstS   = (int*)           alloc((size_t)EtPad * 4);
  unsigned short* W1T    = (unsigned short*)alloc((size_t)3 * 65536 * 2);
  unsigned short* W2T    = (unsigned short*)alloc((size_t)3 * 32768 * 2);
  unsigned short* W0T    = (unsigned short*)alloc((size_t)3 * 65536 * 2);
  unsigned short* Wcat   = (unsigned short*)alloc((size_t)3 * 98304 * 2);
  unsigned short* encWT  = (unsigned short*)alloc((size_t)8192 * 2);
  unsigned short* dW0T   = (unsigned short*)alloc((size_t)32768 * 2);
  unsigned short* dW1T   = (unsigned short*)alloc((size_t)65536 * 2);
  float*          brz    = (float*)         alloc((size_t)768 * 4);
  float*          binb   = (float*)         alloc((size_t)384 * 4);
  float*          bhnb   = (float*)         alloc((size_t)384 * 4);
  (void)ws_size; (void)n_in; (void)out_size;

  hipMemsetAsync(cnt, 0, (size_t)N * 4, stream);
  hipMemsetAsync(dstS, 0xFF, (size_t)EtPad * 4, stream);
  k_count<<<(E + 255) / 256, 256, 0, stream>>>(ei, cnt, E);
  k_scan<<<1, 1024, 0, stream>>>(cnt, cursor, N);
  k_scatter<<<(Et + 255) / 256, 256, 0, stream>>>(ei, cursor, srcS, dstS, E, N);
  k_wprep<<<(3 * 65536 + 3 * 32768 + 255) / 256, 256, 0, stream>>>(msgW1, msgW2, W1T, W2T);
  k_wprep2<<<(3 * 65536 + 255) / 256, 256, 0, stream>>>(msgW0, W0T);
  k_wprep3<<<(3 * 98304 + 255) / 256, 256, 0, stream>>>(gWih, gWhh, Wcat);
  k_wprep4<<<(108032 + 255) / 256, 256, 0, stream>>>(encW, dW0, dW1, gbih, gbhh,
                                                     encWT, dW0T, dW1T, brz, binb, bhnb);

  int nb64 = (N + 63) / 64;
  k_enc<<<nb64, 256, 0, stream>>>(x, encWT, encb, W0T, msgb0, h, hbuf, Abuf, Bbuf, N);

  int eb = EtPad / 64;
  for (int l = 0; l < 3; l++){
    hipMemsetAsync(aggr, 0, (size_t)N * 128 * 4, stream);
    k_edge<<<eb, 256, 0, stream>>>(srcS, dstS, Abuf, Bbuf,
        W1T + (size_t)l * 65536, W2T + (size_t)l * 32768,
        msgb1 + (size_t)l * 256, msgb2 + (size_t)l * 128,
        aggr);
    int nl = (l < 2) ? (l + 1) : 2;   // weight ptrs unused when doAB=0
    k_gru<<<nb64, 256, 0, stream>>>(aggr, cnt, h, hbuf,
        Wcat + (size_t)l * 98304, brz + (size_t)l * 256,
        binb + (size_t)l * 128, bhnb + (size_t)l * 128,
        (l < 2) ? 1 : 0, W0T + (size_t)nl * 65536, msgb0 + (size_t)nl * 256,
        Abuf, Bbuf, N);
  }
  k_dec<<<nb64, 256, 0, stream>>>(hbuf, dW0T, db0, dW1T, db1, dW2, db2, out, N);
}

// Round 14
// 1523.702 us; speedup vs baseline: 1.0129x; 1.0129x over previous
//
#include <hip/hip_runtime.h>

// ---------- types / helpers ----------
typedef __bf16 bf16x8 __attribute__((ext_vector_type(8)));
typedef float  f32x4  __attribute__((ext_vector_type(4)));

// native cast -> compiler emits v_cvt_pk_bf16_f32 (RNE)
__device__ inline unsigned short f2bf(float f){
  __bf16 b = (__bf16)f;
  return __builtin_bit_cast(unsigned short, b);
}
__device__ inline unsigned int pack2bf(float lo, float hi){
  return (unsigned)f2bf(lo) | ((unsigned)f2bf(hi) << 16);
}
__device__ inline float tanh_fast(float x){
  float e = __builtin_amdgcn_exp2f(x * 2.8853900817779268f);
  return 1.0f - 2.0f * __builtin_amdgcn_rcpf(e + 1.0f);
}
__device__ inline float sigmoid_fast(float x){
  float e = __builtin_amdgcn_exp2f(x * -1.4426950408889634f);
  return __builtin_amdgcn_rcpf(1.0f + e);
}
__device__ inline float bflo(unsigned int u){ return __uint_as_float(u << 16); }
__device__ inline float bfhi(unsigned int u){ return __uint_as_float(u & 0xffff0000u); }

// barrier WITHOUT vmem drain (lgkmcnt-only; LDS-safe, proven r7/r8)
__device__ __forceinline__ void bar_nodrain(){
  asm volatile("s_waitcnt lgkmcnt(0)" ::: "memory");
  __builtin_amdgcn_s_barrier();
}

// position of the n-th set bit; returns 0 if n >= popcount(m) (caller predicates)
__device__ inline int nthbit(unsigned long long m, int n){
  for (int k = 0; k < n; k++) m &= m - 1;
  return m ? (int)__builtin_ctzll(m) : 0;
}

// ---------- counts ----------
__global__ void k_count(const int* __restrict__ ei, int* __restrict__ cnt, int E){
  int e = blockIdx.x * 256 + threadIdx.x;
  if (e < E) atomicAdd(&cnt[ei[E + e]], 1);
}

// ---------- exclusive scan of (cnt[v]+1) ----------
__global__ __launch_bounds__(1024) void k_scan(const int* __restrict__ cnt, int* __restrict__ cursor, int N){
  __shared__ int partial[1024];
  int t = threadIdx.x;
  int chunk = (N + 1023) / 1024;
  int lo = t * chunk, hi = min(lo + chunk, N);
  int s = 0;
  for (int v = lo; v < hi; v++) s += cnt[v] + 1;
  partial[t] = s;
  __syncthreads();
  for (int off = 1; off < 1024; off <<= 1){
    int val = (t >= off) ? partial[t - off] : 0;
    __syncthreads();
    partial[t] += val;
    __syncthreads();
  }
  int base = (t == 0) ? 0 : partial[t - 1];
  for (int v = lo; v < hi; v++){ cursor[v] = base; base += cnt[v] + 1; }
}

// ---------- counting-sort scatter by dst ----------
__global__ void k_scatter(const int* __restrict__ ei, int* __restrict__ cursor,
                          int* __restrict__ srcS, int* __restrict__ dstS, int E, int N){
  int i = blockIdx.x * 256 + threadIdx.x;
  int Et = E + N;
  if (i >= Et) return;
  int s, d;
  if (i < E){ s = ei[i]; d = ei[E + i]; } else { s = d = i - E; }
  int pos = atomicAdd(&cursor[d], 1);
  srcS[pos] = s; dstS[pos] = d;
}

// ---------- weight prep: W1T, W2T ----------
__global__ void k_wprep(const float* __restrict__ msgW1, const float* __restrict__ msgW2,
                        unsigned short* __restrict__ W1T, unsigned short* __restrict__ W2T){
  int idx = blockIdx.x * 256 + threadIdx.x;
  if (idx < 3 * 256 * 256){
    int l = idx >> 16, r = idx & 65535; int n = r >> 8, k = r & 255;
    W1T[idx] = f2bf(msgW1[(size_t)l * 65536 + k * 256 + n]);
  }
  int i2 = idx - 3 * 65536;
  if (i2 >= 0 && i2 < 3 * 128 * 256){
    int l = i2 >> 15, r = i2 & 32767; int hh = r >> 8, k = r & 255;
    W2T[i2] = f2bf(msgW2[(size_t)l * 32768 + k * 128 + hh]);
  }
}

// ---------- weight prep: W0T[l][half][c][k] ----------
__global__ void k_wprep2(const float* __restrict__ msgW0, unsigned short* __restrict__ W0T){
  int idx = blockIdx.x * 256 + threadIdx.x;
  if (idx >= 3 * 2 * 256 * 128) return;
  int l = idx / 65536, r = idx % 65536;
  int half = r >> 15, r2 = r & 32767, c = r2 >> 7, k = r2 & 127;
  W0T[idx] = f2bf(msgW0[(size_t)l * 65536 + (half * 128 + k) * 256 + c]);
}

// ---------- weight prep: Wcat[l][j][k] = [Wih[j] || Whh[j]] ----------
__global__ void k_wprep3(const float* __restrict__ gWih, const float* __restrict__ gWhh,
                         unsigned short* __restrict__ Wcat){
  int idx = blockIdx.x * 256 + threadIdx.x;
  if (idx >= 3 * 384 * 256) return;
  int l = idx / 98304, r = idx % 98304, j = r >> 8, k = r & 255;
  float v = (k < 128) ? gWih[((size_t)l * 384 + j) * 128 + k]
                      : gWhh[((size_t)l * 384 + j) * 128 + (k - 128)];
  Wcat[idx] = f2bf(v);
}

// ---------- weight prep: encWT, dW0T, dW1T, GRU biases ----------
__global__ void k_wprep4(const float* __restrict__ encW, const float* __restrict__ dW0,
                         const float* __restrict__ dW1,
                         const float* __restrict__ gbih, const float* __restrict__ gbhh,
                         unsigned short* __restrict__ encWT, unsigned short* __restrict__ dW0T,
                         unsigned short* __restrict__ dW1T,
                         float* __restrict__ brz, float* __restrict__ bin, float* __restrict__ bhn){
  int idx = blockIdx.x * 256 + threadIdx.x;
  if (idx < 8192){ int c = idx >> 6, k = idx & 63; encWT[idx] = f2bf(encW[k * 128 + c]); return; }
  idx -= 8192;
  if (idx < 32768){ int c = idx >> 7, k = idx & 127; dW0T[idx] = f2bf(dW0[k * 256 + c]); return; }
  idx -= 32768;
  if (idx < 65536){ int c = idx >> 8, k = idx & 255; dW1T[idx] = f2bf(dW1[k * 256 + c]); return; }
  idx -= 65536;
  if (idx < 768){ int l = idx >> 8, j = idx & 255; brz[idx] = gbih[l * 384 + j] + gbhh[l * 384 + j]; return; }
  idx -= 768;
  if (idx < 384){ int l = idx >> 7, j = idx & 127; bin[idx] = gbih[l * 384 + 256 + j]; return; }
  idx -= 384;
  if (idx < 384){ int l = idx >> 7, j = idx & 127; bhn[idx] = gbhh[l * 384 + 256 + j]; return; }
}

// ---------- encoder: h = tanh(x @ encW + b), MFMA, 64 nodes/block ----------
__global__ __launch_bounds__(256) void k_enc(const float* __restrict__ x,
        const unsigned short* __restrict__ encWT, const float* __restrict__ encb,
        float* __restrict__ h, unsigned short* __restrict__ hb, int N){
  __shared__ __align__(16) unsigned char xb[64 * 128];
  int n0 = blockIdx.x * 64, t = threadIdx.x;
  #pragma unroll
  for (int p = 0; p < 2; p++){
    int i = t + p * 256;
    int row = i >> 3, ch = i & 7;
    int node = n0 + row;
    unsigned int o[4] = {0,0,0,0};
    if (node < N){
      const float* s = x + (size_t)node * 64 + ch * 8;
      float4 a = *(const float4*)s, b = *(const float4*)(s + 4);
      o[0] = pack2bf(a.x, a.y);
      o[1] = pack2bf(a.z, a.w);
      o[2] = pack2bf(b.x, b.y);
      o[3] = pack2bf(b.z, b.w);
    }
    *(uint4*)(xb + row * 128 + ((ch * 16) ^ ((row & 7) << 4))) = make_uint4(o[0], o[1], o[2], o[3]);
  }
  __syncthreads();
  int wv = t >> 6, lane = t & 63, l15 = lane & 15, kg = lane >> 4;
  int c32 = wv * 32;
  f32x4 acc[2][4];
  #pragma unroll
  for (int ct = 0; ct < 2; ct++){
    int c = c32 + ct * 16 + kg * 4;
    float4 be = *(const float4*)(encb + c);
    f32x4 binit = {be.x, be.y, be.z, be.w};
    #pragma unroll
    for (int b_ = 0; b_ < 4; b_++) acc[ct][b_] = binit;
  }
  const unsigned char* wp = (const unsigned char*)encWT;   // [128][128B]
  #pragma unroll
  for (int ks = 0; ks < 2; ks++){
    int koff = ks * 64 + kg * 16;
    bf16x8 bfr[4], afr[2];
    #pragma unroll
    for (int nt = 0; nt < 4; nt++){
      int row = nt * 16 + l15;
      bfr[nt] = *(const bf16x8*)(xb + row * 128 + (koff ^ ((row & 7) << 4)));
    }
    #pragma unroll
    for (int ct = 0; ct < 2; ct++)
      afr[ct] = *(const bf16x8*)(wp + (size_t)(c32 + ct * 16 + l15) * 128 + koff);
    #pragma unroll
    for (int ct = 0; ct < 2; ct++)
      #pragma unroll
      for (int nt = 0; nt < 4; nt++)
        acc[ct][nt] = __builtin_amdgcn_mfma_f32_16x16x32_bf16(afr[ct], bfr[nt], acc[ct][nt], 0, 0, 0);
  }
  #pragma unroll
  for (int ct = 0; ct < 2; ct++){
    int c = c32 + ct * 16 + kg * 4;
    #pragma unroll
    for (int nt = 0; nt < 4; nt++){
      int node = n0 + nt * 16 + l15;
      if (node >= N) continue;
      f32x4 v = acc[ct][nt];
      float o0 = tanh_fast(v[0]), o1 = tanh_fast(v[1]);
      float o2 = tanh_fast(v[2]), o3 = tanh_fast(v[3]);
      float4 fo; fo.x = o0; fo.y = o1; fo.z = o2; fo.w = o3;
      *(float4*)(h + (size_t)node * 128 + c) = fo;
      uint2 bo; bo.x = pack2bf(o0, o1); bo.y = pack2bf(o2, o3);
      *(uint2*)(hb + (size_t)node * 128 + c) = bo;
    }
  }
}

// ---------- A/B projection: MFMA, 64 nodes/block. A includes +b0 (folded) ----------
__global__ __launch_bounds__(256) void k_ab(const unsigned short* __restrict__ hb,
        const unsigned short* __restrict__ W0T, const float* __restrict__ b0,
        unsigned short* __restrict__ A, unsigned short* __restrict__ B, int N){
  __shared__ __align__(16) unsigned char ub[64 * 256];
  int n0 = blockIdx.x * 64, t = threadIdx.x;
  #pragma unroll
  for (int p = 0; p < 4; p++){
    int i = t + p * 256;
    int row = i >> 4, ch = i & 15;
    int node = n0 + row;
    uint4 v = (node < N) ? *(const uint4*)(hb + (size_t)node * 128 + ch * 8) : make_uint4(0,0,0,0);
    *(uint4*)(ub + row * 256 + ((ch * 16) ^ ((row & 7) << 4))) = v;
  }
  __syncthreads();
  int wv = t >> 6, lane = t & 63, l15 = lane & 15, kg = lane >> 4;
  f32x4 zero = {0.f, 0.f, 0.f, 0.f};
  int c64 = wv * 64;
  f32x4 accA[4][4], accB[4][4];
  #pragma unroll
  for (int ct = 0; ct < 4; ct++){
    int c = c64 + ct * 16 + kg * 4;
    float4 b4 = *(const float4*)(b0 + c);
    f32x4 binit = {b4.x, b4.y, b4.z, b4.w};
    #pragma unroll
    for (int b_ = 0; b_ < 4; b_++){ accA[ct][b_] = binit; accB[ct][b_] = zero; }
  }
  const unsigned char* wa = (const unsigned char*)W0T;       // [256][256B]
  const unsigned char* wb = wa + 65536;
  #pragma unroll
  for (int ks = 0; ks < 4; ks++){
    int koff = ks * 64 + kg * 16;
    bf16x8 bfr[4];
    #pragma unroll
    for (int nt = 0; nt < 4; nt++){
      int row = nt * 16 + l15;
      bfr[nt] = *(const bf16x8*)(ub + row * 256 + (koff ^ ((row & 7) << 4)));
    }
    bf16x8 afA[4], afB[4];
    #pragma unroll
    for (int ct = 0; ct < 4; ct++){
      int r = c64 + ct * 16 + l15;
      afA[ct] = *(const bf16x8*)(wa + (size_t)r * 256 + koff);
      afB[ct] = *(const bf16x8*)(wb + (size_t)r * 256 + koff);
    }
    #pragma unroll
    for (int ct = 0; ct < 4; ct++)
      #pragma unroll
      for (int nt = 0; nt < 4; nt++){
        accA[ct][nt] = __builtin_amdgcn_mfma_f32_16x16x32_bf16(afA[ct], bfr[nt], accA[ct][nt], 0, 0, 0);
        accB[ct][nt] = __builtin_amdgcn_mfma_f32_16x16x32_bf16(afB[ct], bfr[nt], accB[ct][nt], 0, 0, 0);
      }
  }
  #pragma unroll
  for (int ct = 0; ct < 4; ct++){
    int c = c64 + ct * 16 + kg * 4;
    #pragma unroll
    for (int nt = 0; nt < 4; nt++){
      int node = n0 + nt * 16 + l15;
      if (node >= N) continue;
      f32x4 va = accA[ct][nt], vb = accB[ct][nt];
      uint2 oa, ob;
      oa.x = pack2bf(va[0], va[1]); oa.y = pack2bf(va[2], va[3]);
      ob.x = pack2bf(vb[0], vb[1]); ob.y = pack2bf(vb[2], vb[3]);
      *(uint2*)(A + (size_t)node * 256 + c) = oa;
      *(uint2*)(B + (size_t)node * 256 + c) = ob;
    }
  }
}

// ---------- fused edge MLP + segmented aggregation ----------
// r12 structure (64-edge tile, et=4 reuse, 4-pass split-K t1q, 40KB LDS ->
// 4 blocks/CU). Segment info precomputed UNIFORMLY (lane s holds seg s); P5
// runs a uniform 8-iteration schedule with all shfls outside predication.
__global__ __launch_bounds__(256, 4) void k_edge(
        const int* __restrict__ srcS, const int* __restrict__ dstS,
        const unsigned short* __restrict__ Abuf, const unsigned short* __restrict__ Bbuf,
        const unsigned short* __restrict__ W1T, const unsigned short* __restrict__ W2T,
        const float* __restrict__ b1, const float* __restrict__ b2,
        float* __restrict__ aggr){
  __shared__ __align__(16) unsigned char lds[40960];  // [0,32768): t0 (bf16) -> m (f32); [32768,40960): t1q
  unsigned char* t0  = lds;
  unsigned char* t1q = lds + 32768;
  int t = threadIdx.x;
  int wv = t >> 6, lane = t & 63, l15 = lane & 15, kg = lane >> 4;
  int e0 = blockIdx.x * 64;

  // every wave holds all 64 (src,dst) pairs in its lanes
  int sv = srcS[e0 + lane];
  int dv = dstS[e0 + lane];

  // ---- gather: 16 loads/thread in flight (uniform control flow)
  int chunk = lane & 31;
  int rbase = wv * 2 + (lane >> 5);   // 0..7 across the block
  uint4 av[8], bv[8];
  #pragma unroll
  for (int p = 0; p < 8; p++){
    int row = p * 8 + rbase;
    int d = __shfl(dv, row), s = __shfl(sv, row);
    if (d >= 0){
      av[p] = *(const uint4*)(Abuf + (size_t)d * 256 + chunk * 8);
      bv[p] = *(const uint4*)(Bbuf + (size_t)s * 256 + chunk * 8);
    } else { av[p] = make_uint4(0,0,0,0); bv[p] = make_uint4(0,0,0,0); }
  }

  // ---- segment detection (per-wave redundant; overlaps gather latency)
  int prevd = __shfl(dv, (lane == 0) ? 0 : (lane - 1));
  bool valid = (dv >= 0);
  bool flag  = valid && (lane == 0 || prevd != dv);
  unsigned long long sm  = __ballot(flag);
  unsigned long long ivm = __ballot(!valid);
  int nseg   = (int)__popcll(sm);
  int endAll = 64 - (int)__popcll(ivm);   // invalid entries are a suffix

  // ---- UNIFORM per-segment precompute: lane s holds segment s's {start,end,dst}
  int segSt, segEn, segD;
  {
    int st_ = nthbit(sm, lane);                       // 0 if lane >= nseg (guarded use)
    int en_ = (lane + 1 < nseg) ? nthbit(sm, lane + 1) : endAll;
    segSt = st_; segEn = en_;
    segD  = __shfl(dv, st_);                          // all 64 lanes execute
  }

  // ---- P1: tanh(a+b) -> t0 (XOR-swizzled); b0 pre-folded into A
  #pragma unroll
  for (int p = 0; p < 8; p++){
    int r = p * 8 + rbase;
    unsigned int o[4]; unsigned int ua, ub;
    ua = av[p].x; ub = bv[p].x;
    o[0] = pack2bf(tanh_fast(bflo(ua)+bflo(ub)), tanh_fast(bfhi(ua)+bfhi(ub)));
    ua = av[p].y; ub = bv[p].y;
    o[1] = pack2bf(tanh_fast(bflo(ua)+bflo(ub)), tanh_fast(bfhi(ua)+bfhi(ub)));
    ua = av[p].z; ub = bv[p].z;
    o[2] = pack2bf(tanh_fast(bflo(ua)+bflo(ub)), tanh_fast(bfhi(ua)+bfhi(ub)));
    ua = av[p].w; ub = bv[p].w;
    o[3] = pack2bf(tanh_fast(bflo(ua)+bflo(ub)), tanh_fast(bfhi(ua)+bfhi(ub)));
    *(uint4*)(t0 + r * 512 + ((chunk * 16) ^ ((r & 7) << 4))) = make_uint4(o[0],o[1],o[2],o[3]);
  }
  bar_nodrain();

  const unsigned char* w1b = (const unsigned char*)W1T;
  const unsigned char* w2b = (const unsigned char*)W2T;
  int hbase = wv * 32;

  f32x4 acc2[2][4];                      // GEMM2 accumulator across 4 K-passes
  #pragma unroll
  for (int ht = 0; ht < 2; ht++){
    int hb_ = hbase + ht * 16 + kg * 4;
    float4 c4 = *(const float4*)(b2 + hb_);
    f32x4 binit = {c4.x, c4.y, c4.z, c4.w};
    #pragma unroll
    for (int b_ = 0; b_ < 4; b_++) acc2[ht][b_] = binit;
  }

  #pragma unroll
  for (int pass = 0; pass < 4; pass++){
    // ---- GEMM1 pass: n-slice [pass*64, +64); wave owns 16 n
    {
      int nbase = pass * 64 + wv * 16;
      f32x4 acc[4];
      {
        int ng = nbase + kg * 4;
        float4 c4 = *(const float4*)(b1 + ng);
        f32x4 binit = {c4.x, c4.y, c4.z, c4.w};
        #pragma unroll
        for (int b_ = 0; b_ < 4; b_++) acc[b_] = binit;
      }
      #pragma unroll
      for (int ks = 0; ks < 8; ks++){
        int koff = ks * 64 + kg * 16;
        bf16x8 afr = *(const bf16x8*)(w1b + (size_t)(nbase + l15) * 512 + koff);
        bf16x8 bfr[4];
        #pragma unroll
        for (int et = 0; et < 4; et++){
          int row = et * 16 + l15;
          bfr[et] = *(const bf16x8*)(t0 + row * 512 + (koff ^ ((row & 7) << 4)));
        }
        #pragma unroll
        for (int et = 0; et < 4; et++)
          acc[et] = __builtin_amdgcn_mfma_f32_16x16x32_bf16(afr, bfr[et], acc[et], 0, 0, 0);
      }
      int nl2 = (wv * 16 + kg * 4) * 2;    // byte offset in 128B t1q row
      #pragma unroll
      for (int et = 0; et < 4; et++){
        int edge = et * 16 + l15;
        f32x4 v = acc[et];
        unsigned int p0 = pack2bf(tanh_fast(v[0]), tanh_fast(v[1]));
        unsigned int p1 = pack2bf(tanh_fast(v[2]), tanh_fast(v[3]));
        *(uint2*)(t1q + edge * 128 + (nl2 ^ ((edge & 7) << 4))) = make_uint2(p0, p1);
      }
    }
    bar_nodrain();

    // ---- GEMM2 partial: K-slice = this pass's 64 n; accumulate acc2
    #pragma unroll
    for (int ks = 0; ks < 2; ks++){
      int koff  = ks * 64 + kg * 16;          // within 128B t1q row
      int wkoff = pass * 128 + koff;          // within 512B W2T row
      bf16x8 afr[2], bfr[4];
      #pragma unroll
      for (int ht = 0; ht < 2; ht++)
        afr[ht] = *(const bf16x8*)(w2b + (size_t)(hbase + ht * 16 + l15) * 512 + wkoff);
      #pragma unroll
      for (int et = 0; et < 4; et++){
        int row = et * 16 + l15;
        bfr[et] = *(const bf16x8*)(t1q + row * 128 + (koff ^ ((row & 7) << 4)));
      }
      #pragma unroll
      for (int ht = 0; ht < 2; ht++)
        #pragma unroll
        for (int et = 0; et < 4; et++)
          acc2[ht][et] = __builtin_amdgcn_mfma_f32_16x16x32_bf16(afr[ht], bfr[et], acc2[ht][et], 0, 0, 0);
    }
    bar_nodrain();   // t1q reuse next pass; t0 still read by later passes
  }

  // ---- m epilogue -> t0 (f32 [64][128]; t0 bf16 data dead after pass 3)
  #pragma unroll
  for (int ht = 0; ht < 2; ht++){
    int hb_ = hbase + ht * 16 + kg * 4;
    int cch = hb_ >> 2;
    #pragma unroll
    for (int et = 0; et < 4; et++){
      int edge = et * 16 + l15;
      f32x4 v = acc2[ht][et];
      float4 o; o.x = v[0]; o.y = v[1]; o.z = v[2]; o.w = v[3];
      *(float4*)(t0 + edge * 512 + ((cch ^ (edge & 7)) << 4)) = o;
    }
  }
  bar_nodrain();

  // ---- P5: segmented reduce, UNIFORM 8-iteration schedule (shfls all-active);
  //      LDS-reduce + atomics predicated on s < nseg.
  {
    int c = lane & 31;
    int sstr = wv * 2 + (lane >> 5);     // 8 segment streams
    #pragma unroll
    for (int s0 = 0; s0 < 8; s0++){
      int s = sstr + s0 * 8;             // s <= 63 always
      int st = __shfl(segSt, s);
      int en = __shfl(segEn, s);
      int d  = __shfl(segD,  s);
      if (s < nseg){
        float4 sum; sum.x = sum.y = sum.z = sum.w = 0.f;
        for (int e = st; e < en; e++){
          float4 v = *(const float4*)(t0 + e * 512 + ((c ^ (e & 7)) << 4));
          sum.x += v.x; sum.y += v.y; sum.z += v.z; sum.w += v.w;
        }
        float* base = aggr + (size_t)d * 128 + c * 4;
        atomicAdd(base + 0, sum.x);
        atomicAdd(base + 1, sum.y);
        atomicAdd(base + 2, sum.z);
        atomicAdd(base + 3, sum.w);
      }
    }
  }
}

// ---------- GRU cell update: MFMA, 64 nodes/block ----------
__global__ __launch_bounds__(256) void k_gru(const float* __restrict__ aggr, const int* __restrict__ cnt,
    float* __restrict__ h, unsigned short* __restrict__ hb,
    const unsigned short* __restrict__ Wcat, const float* __restrict__ brz,
    const float* __restrict__ bin, const float* __restrict__ bhn, int N){
  __shared__ __align__(16) unsigned char u[64 * 512];   // [aggr*inv || h] bf16 swizzled
  __shared__ __align__(16) unsigned char hf[64 * 512];  // h f32 swizzled
  int n0 = blockIdx.x * 64, t = threadIdx.x;
  {
    int row = t >> 2, node = n0 + row;
    int q4 = t & 3;
    bool isA = q4 < 2;
    float inv = 0.f;
    if (isA && node < N) inv = __builtin_amdgcn_rcpf((float)(cnt[node] + 1));
    #pragma unroll
    for (int p = 0; p < 8; p++){
      int ch = q4 * 8 + p;
      unsigned int o[4] = {0,0,0,0};
      if (node < N){
        if (isA){
          const float* s = aggr + (size_t)node * 128 + ch * 8;
          float4 a = *(const float4*)s, b = *(const float4*)(s + 4);
          a.x *= inv; a.y *= inv; a.z *= inv; a.w *= inv;
          b.x *= inv; b.y *= inv; b.z *= inv; b.w *= inv;
          o[0] = pack2bf(a.x, a.y); o[1] = pack2bf(a.z, a.w);
          o[2] = pack2bf(b.x, b.y); o[3] = pack2bf(b.z, b.w);
        } else {
          const float* s = h + (size_t)node * 128 + (ch - 16) * 8;
          float4 a = *(const float4*)s, b = *(const float4*)(s + 4);
          o[0] = pack2bf(a.x, a.y); o[1] = pack2bf(a.z, a.w);
          o[2] = pack2bf(b.x, b.y); o[3] = pack2bf(b.z, b.w);
          int c2 = (ch - 16) * 2;
          *(float4*)(hf + row * 512 + ((c2 * 16) ^ ((row & 7) << 4))) = a;
          *(float4*)(hf + row * 512 + (((c2 + 1) * 16) ^ ((row & 7) << 4))) = b;
        }
      }
      *(uint4*)(u + row * 512 + ((ch * 16) ^ ((row & 7) << 4))) = make_uint4(o[0], o[1], o[2], o[3]);
    }
  }
  __syncthreads();
  int wv = t >> 6, lane = t & 63, l15 = lane & 15, kg = lane >> 4;
  int j32 = wv * 32;
  f32x4 accR[2][4], accZ[2][4], accI[2][4], accH[2][4];
  #pragma unroll
  for (int jt = 0; jt < 2; jt++){
    int j = j32 + jt * 16 + kg * 4;
    float4 br = *(const float4*)(brz + j);
    float4 bz = *(const float4*)(brz + 128 + j);
    float4 bi = *(const float4*)(bin + j);
    float4 bh = *(const float4*)(bhn + j);
    f32x4 vr = {br.x, br.y, br.z, br.w};
    f32x4 vz = {bz.x, bz.y, bz.z, bz.w};
    f32x4 vi = {bi.x, bi.y, bi.z, bi.w};
    f32x4 vh = {bh.x, bh.y, bh.z, bh.w};
    #pragma unroll
    for (int b_ = 0; b_ < 4; b_++){ accR[jt][b_] = vr; accZ[jt][b_] = vz; accI[jt][b_] = vi; accH[jt][b_] = vh; }
  }
  const unsigned char* wc = (const unsigned char*)Wcat;     // [384][512B]
  #pragma unroll
  for (int ks = 0; ks < 8; ks++){
    int koff = ks * 64 + kg * 16;
    bf16x8 bfr[4];
    #pragma unroll
    for (int nt = 0; nt < 4; nt++){
      int row = nt * 16 + l15;
      bfr[nt] = *(const bf16x8*)(u + row * 512 + (koff ^ ((row & 7) << 4)));
    }
    bf16x8 aR[2], aZ[2], aN[2];
    #pragma unroll
    for (int jt = 0; jt < 2; jt++){
      int jr = j32 + jt * 16 + l15;
      aR[jt] = *(const bf16x8*)(wc + (size_t)jr * 512 + koff);
      aZ[jt] = *(const bf16x8*)(wc + (size_t)(128 + jr) * 512 + koff);
      aN[jt] = *(const bf16x8*)(wc + (size_t)(256 + jr) * 512 + koff);
    }
    #pragma unroll
    for (int jt = 0; jt < 2; jt++)
      #pragma unroll
      for (int nt = 0; nt < 4; nt++){
        accR[jt][nt] = __builtin_amdgcn_mfma_f32_16x16x32_bf16(aR[jt], bfr[nt], accR[jt][nt], 0, 0, 0);
        accZ[jt][nt] = __builtin_amdgcn_mfma_f32_16x16x32_bf16(aZ[jt], bfr[nt], accZ[jt][nt], 0, 0, 0);
      }
    if (ks < 4){
      #pragma unroll
      for (int jt = 0; jt < 2; jt++)
        #pragma unroll
        for (int nt = 0; nt < 4; nt++)
          accI[jt][nt] = __builtin_amdgcn_mfma_f32_16x16x32_bf16(aN[jt], bfr[nt], accI[jt][nt], 0, 0, 0);
    } else {
      #pragma unroll
      for (int jt = 0; jt < 2; jt++)
        #pragma unroll
        for (int nt = 0; nt < 4; nt++)
          accH[jt][nt] = __builtin_amdgcn_mfma_f32_16x16x32_bf16(aN[jt], bfr[nt], accH[jt][nt], 0, 0, 0);
    }
  }
  #pragma unroll
  for (int jt = 0; jt < 2; jt++){
    int j = j32 + jt * 16 + kg * 4;
    #pragma unroll
    for (int nt = 0; nt < 4; nt++){
      int rloc = nt * 16 + l15;
      int node = n0 + rloc;
      if (node >= N) continue;
      float4 hold = *(const float4*)(hf + rloc * 512 + ((j * 4) ^ ((rloc & 7) << 4)));
      f32x4 vr = accR[jt][nt], vz = accZ[jt][nt], vi = accI[jt][nt], vh = accH[jt][nt];
      float o[4];
      {
        float r0 = sigmoid_fast(vr[0]), z0 = sigmoid_fast(vz[0]);
        o[0] = (1.f - z0) * tanh_fast(vi[0] + r0 * vh[0]) + z0 * hold.x;
        float r1 = sigmoid_fast(vr[1]), z1 = sigmoid_fast(vz[1]);
        o[1] = (1.f - z1) * tanh_fast(vi[1] + r1 * vh[1]) + z1 * hold.y;
        float r2 = sigmoid_fast(vr[2]), z2 = sigmoid_fast(vz[2]);
        o[2] = (1.f - z2) * tanh_fast(vi[2] + r2 * vh[2]) + z2 * hold.z;
        float r3 = sigmoid_fast(vr[3]), z3 = sigmoid_fast(vz[3]);
        o[3] = (1.f - z3) * tanh_fast(vi[3] + r3 * vh[3]) + z3 * hold.w;
      }
      float4 fo; fo.x = o[0]; fo.y = o[1]; fo.z = o[2]; fo.w = o[3];
      *(float4*)(h + (size_t)node * 128 + j) = fo;
      uint2 bo; bo.x = pack2bf(o[0], o[1]); bo.y = pack2bf(o[2], o[3]);
      *(uint2*)(hb + (size_t)node * 128 + j) = bo;
    }
  }
}

// ---------- decoder: MFMA, 64 nodes/block ----------
__global__ __launch_bounds__(256) void k_dec(const unsigned short* __restrict__ hb,
    const unsigned short* __restrict__ dW0T, const float* __restrict__ db0,
    const unsigned short* __restrict__ dW1T, const float* __restrict__ db1,
    const float* __restrict__ dW2, const float* __restrict__ db2,
    float* __restrict__ out, int N){
  __shared__ __align__(16) unsigned char ub[64 * 256];
  __shared__ __align__(16) unsigned char y1[64 * 512];
  __shared__ __align__(16) unsigned char y2[64 * 1024];
  int n0 = blockIdx.x * 64, t = threadIdx.x;
  #pragma unroll
  for (int p = 0; p < 4; p++){
    int i = t + p * 256;
    int row = i >> 4, ch = i & 15;
    int node = n0 + row;
    uint4 v = (node < N) ? *(const uint4*)(hb + (size_t)node * 128 + ch * 8) : make_uint4(0,0,0,0);
    *(uint4*)(ub + row * 256 + ((ch * 16) ^ ((row & 7) << 4))) = v;
  }
  __syncthreads();
  int wv = t >> 6, lane = t & 63, l15 = lane & 15, kg = lane >> 4;
  int c64 = wv * 64;
  {
    f32x4 acc[4][4];
    #pragma unroll
    for (int ct = 0; ct < 4; ct++){
      int c = c64 + ct * 16 + kg * 4;
      float4 b4 = *(const float4*)(db0 + c);
      f32x4 binit = {b4.x, b4.y, b4.z, b4.w};
      #pragma unroll
      for (int b_ = 0; b_ < 4; b_++) acc[ct][b_] = binit;
    }
    const unsigned char* wp = (const unsigned char*)dW0T;   // [256][256B]
    #pragma unroll
    for (int ks = 0; ks < 4; ks++){
      int koff = ks * 64 + kg * 16;
      bf16x8 bfr[4], afr[4];
      #pragma unroll
      for (int nt = 0; nt < 4; nt++){
        int row = nt * 16 + l15;
        bfr[nt] = *(const bf16x8*)(ub + row * 256 + (koff ^ ((row & 7) << 4)));
      }
      #pragma unroll
      for (int ct = 0; ct < 4; ct++)
        afr[ct] = *(const bf16x8*)(wp + (size_t)(c64 + ct * 16 + l15) * 256 + koff);
      #pragma unroll
      for (int ct = 0; ct < 4; ct++)
        #pragma unroll
        for (int nt = 0; nt < 4; nt++)
          acc[ct][nt] = __builtin_amdgcn_mfma_f32_16x16x32_bf16(afr[ct], bfr[nt], acc[ct][nt], 0, 0, 0);
    }
    #pragma unroll
    for (int ct = 0; ct < 4; ct++){
      int c = c64 + ct * 16 + kg * 4;
      #pragma unroll
      for (int nt = 0; nt < 4; nt++){
        int row = nt * 16 + l15;
        f32x4 v = acc[ct][nt];
        unsigned int p0 = pack2bf(tanh_fast(v[0]), tanh_fast(v[1]));
        unsigned int p1 = pack2bf(tanh_fast(v[2]), tanh_fast(v[3]));
        *(uint2*)(y1 + row * 512 + ((c * 2) ^ ((row & 7) << 4))) = make_uint2(p0, p1);
      }
    }
  }
  __syncthreads();
  {
    f32x4 acc[4][4];
    #pragma unroll
    for (int ct = 0; ct < 4; ct++){
      int c = c64 + ct * 16 + kg * 4;
      float4 b4 = *(const float4*)(db1 + c);
      f32x4 binit = {b4.x, b4.y, b4.z, b4.w};
      #pragma unroll
      for (int b_ = 0; b_ < 4; b_++) acc[ct][b_] = binit;
    }
    const unsigned char* wp = (const unsigned char*)dW1T;   // [256][512B]
    #pragma unroll
    for (int ks = 0; ks < 8; ks++){
      int koff = ks * 64 + kg * 16;
      bf16x8 bfr[4], afr[4];
      #pragma unroll
      for (int nt = 0; nt < 4; nt++){
        int row = nt * 16 + l15;
        bfr[nt] = *(const bf16x8*)(y1 + row * 512 + (koff ^ ((row & 7) << 4)));
      }
      #pragma unroll
      for (int ct = 0; ct < 4; ct++)
        afr[ct] = *(const bf16x8*)(wp + (size_t)(c64 + ct * 16 + l15) * 512 + koff);
      #pragma unroll
      for (int ct = 0; ct < 4; ct++)
        #pragma unroll
        for (int nt = 0; nt < 4; nt++)
          acc[ct][nt] = __builtin_amdgcn_mfma_f32_16x16x32_bf16(afr[ct], bfr[nt], acc[ct][nt], 0, 0, 0);
    }
    #pragma unroll
    for (int ct = 0; ct < 4; ct++){
      int c = c64 + ct * 16 + kg * 4;
      #pragma unroll
      for (int nt = 0; nt < 4; nt++){
        int row = nt * 16 + l15;
        f32x4 v = acc[ct][nt];
        float4 o;
        o.x = tanh_fast(v[0]); o.y = tanh_fast(v[1]);
        o.z = tanh_fast(v[2]); o.w = tanh_fast(v[3]);
        *(float4*)(y2 + row * 1024 + ((c * 4) ^ ((row & 7) << 4))) = o;
      }
    }
  }
  __syncthreads();
  {
    int node = t >> 2, part = t & 3;
    float p = 0.f;
    #pragma unroll
    for (int q = 0; q < 16; q++){
      int c = part * 64 + q * 4;
      float4 v = *(const float4*)(y2 + node * 1024 + ((c * 4) ^ ((node & 7) << 4)));
      float4 w = *(const float4*)(dW2 + c);
      p += v.x * w.x + v.y * w.y + v.z * w.z + v.w * w.w;
    }
    p += __shfl_down(p, 2, 4);
    p += __shfl_down(p, 1, 4);
    if (part == 0 && (n0 + node) < N) out[n0 + node] = p + db2[0];
  }
}

// ---------- launcher ----------
extern "C" void kernel_launch(void* const* d_in, const int* in_sizes, int n_in,
                              void* d_out, int out_size, void* d_ws, size_t ws_size,
                              hipStream_t stream){
  const float* x     = (const float*)d_in[0];
  const int*   ei    = (const int*)  d_in[1];
  const float* encW  = (const float*)d_in[2];
  const float* encb  = (const float*)d_in[3];
  const float* msgW0 = (const float*)d_in[4];
  const float* msgb0 = (const float*)d_in[5];
  const float* msgW1 = (const float*)d_in[6];
  const float* msgb1 = (const float*)d_in[7];
  const float* msgW2 = (const float*)d_in[8];
  const float* msgb2 = (const float*)d_in[9];
  const float* gWih  = (const float*)d_in[10];
  const float* gWhh  = (const float*)d_in[11];
  const float* gbih  = (const float*)d_in[12];
  const float* gbhh  = (const float*)d_in[13];
  const float* dW0   = (const float*)d_in[14];
  const float* db0   = (const float*)d_in[15];
  const float* dW1   = (const float*)d_in[16];
  const float* db1   = (const float*)d_in[17];
  const float* dW2   = (const float*)d_in[18];
  const float* db2   = (const float*)d_in[19];
  int N = in_sizes[0] / 64;
  int E = in_sizes[1] / 2;
  float* out = (float*)d_out;

  int Et = E + N;
  int EtPad = (Et + 63) & ~63;

  char* ws = (char*)d_ws;
  size_t off = 0;
  auto alloc = [&](size_t bytes)->void*{
    void* p = ws + off; off += (bytes + 255) & ~(size_t)255; return p;
  };
  float*          h      = (float*)         alloc((size_t)N * 128 * 4);
  unsigned short* hbuf   = (unsigned short*)alloc((size_t)N * 128 * 2);
  unsigned short* Abuf   = (unsigned short*)alloc((size_t)N * 256 * 2);
  unsigned short* Bbuf   = (unsigned short*)alloc((size_t)N * 256 * 2);
  float*          aggr   = (float*)         alloc((size_t)N * 128 * 4);
  int*            cnt    = (int*)           alloc((size_t)N * 4);
  int*            cursor = (int*)           alloc((size_t)N * 4);
  int*            srcS   = (int*)           alloc((size_t)EtPad * 4);
  int*            dstS   = (int*)           alloc((size_t)EtPad * 4);
  unsigned short* W1T    = (unsigned short*)alloc((size_t)3 * 65536 * 2);
  unsigned short* W2T    = (unsigned short*)alloc((size_t)3 * 32768 * 2);
  unsigned short* W0T    = (unsigned short*)alloc((size_t)3 * 65536 * 2);
  unsigned short* Wcat   = (unsigned short*)alloc((size_t)3 * 98304 * 2);
  unsigned short* encWT  = (unsigned short*)alloc((size_t)8192 * 2);
  unsigned short* dW0T   = (unsigned short*)alloc((size_t)32768 * 2);
  unsigned short* dW1T   = (unsigned short*)alloc((size_t)65536 * 2);
  float*          brz    = (float*)         alloc((size_t)768 * 4);
  float*          binb   = (float*)         alloc((size_t)384 * 4);
  float*          bhnb   = (float*)         alloc((size_t)384 * 4);
  (void)ws_size; (void)n_in; (void)out_size;

  hipMemsetAsync(cnt, 0, (size_t)N * 4, stream);
  hipMemsetAsync(dstS, 0xFF, (size_t)EtPad * 4, stream);
  k_count<<<(E + 255) / 256, 256, 0, stream>>>(ei, cnt, E);
  k_scan<<<1, 1024, 0, stream>>>(cnt, cursor, N);
  k_scatter<<<(Et + 255) / 256, 256, 0, stream>>>(ei, cursor, srcS, dstS, E, N);
  k_wprep<<<(3 * 65536 + 3 * 32768 + 255) / 256, 256, 0, stream>>>(msgW1, msgW2, W1T, W2T);
  k_wprep2<<<(3 * 65536 + 255) / 256, 256, 0, stream>>>(msgW0, W0T);
  k_wprep3<<<(3 * 98304 + 255) / 256, 256, 0, stream>>>(gWih, gWhh, Wcat);
  k_wprep4<<<(108032 + 255) / 256, 256, 0, stream>>>(encW, dW0, dW1, gbih, gbhh,
                                                     encWT, dW0T, dW1T, brz, binb, bhnb);

  int nb64 = (N + 63) / 64;
  k_enc<<<nb64, 256, 0, stream>>>(x, encWT, encb, h, hbuf, N);

  int eb = EtPad / 64;
  for (int l = 0; l < 3; l++){
    k_ab<<<nb64, 256, 0, stream>>>(hbuf, W0T + (size_t)l * 65536, msgb0 + (size_t)l * 256,
                                   Abuf, Bbuf, N);
    hipMemsetAsync(aggr, 0, (size_t)N * 128 * 4, stream);
    k_edge<<<eb, 256, 0, stream>>>(srcS, dstS, Abuf, Bbuf,
        W1T + (size_t)l * 65536, W2T + (size_t)l * 32768,
        msgb1 + (size_t)l * 256, msgb2 + (size_t)l * 128,
        aggr);
    k_gru<<<nb64, 256, 0, stream>>>(aggr, cnt, h, hbuf,
        Wcat + (size_t)l * 98304, brz + (size_t)l * 256,
        binb + (size_t)l * 128, bhnb + (size_t)l * 128, N);
  }
  k_dec<<<nb64, 256, 0, stream>>>(hbuf, dW0T, db0, dW1T, db1, dW2, db2, out, N);
}